// Round 2
// baseline (26277.820 us; speedup 1.0000x reference)
//
#include <hip/hip_runtime.h>
#include <hip/hip_fp16.h>

#define NTRAJ   256
#define NTP     512
#define NSTEPS  511
#define LATENT  256
#define INPUT   128
#define DEC_OUT 128

#define OUT_VOL ((size_t)NTRAJ * LATENT)                              // 65536
#define OUT_DTS (OUT_VOL + (size_t)NTRAJ * NSTEPS * DEC_OUT)          // 16809984

// Pair-interleaved fp16 weight workspace (offsets in uint32 = half2 units).
// Layout per matrix [K][C]: ws[kp*C + c] = half2(W[2kp][c], W[2kp+1][c]).
#define WU_UG1  0
#define WU_UG2  49152
#define WU_UGT1 81920
#define WU_UGT2 131072
#define WU_RG1  163840
#define WU_RG2  212992
#define WU_NS1  245760
#define WU_NS2  294912
#define WU_DK1  327680
#define WU_DEC  360448
#define WU_TOT  376832

typedef _Float16 h2_t __attribute__((ext_vector_type(2)));
union U32H2 { unsigned int u; h2_t h; };

__device__ __forceinline__ float dot2f(unsigned int wu, unsigned int xu, float acc) {
#if defined(__has_builtin) && __has_builtin(__builtin_amdgcn_fdot2)
    U32H2 a, b; a.u = wu; b.u = xu;
    return __builtin_amdgcn_fdot2(a.h, b.h, acc, false);
#else
    U32H2 a, b; a.u = wu; b.u = xu;
    return acc + (float)a.h.x * (float)b.h.x + (float)a.h.y * (float)b.h.y;
#endif
}

__device__ __forceinline__ float wred(float v) {
    #pragma unroll
    for (int off = 32; off; off >>= 1) v += __shfl_down(v, off, 64);
    return v;
}
__device__ __forceinline__ float fast_sigmoid(float x) { return 1.0f / (1.0f + __expf(-x)); }
__device__ __forceinline__ float fast_tanh(float x) {
    float e = __expf(2.0f * x);
    return 1.0f - 2.0f / (e + 1.0f);
}
// Pack (v_even, v_odd) from adjacent lanes into one half2; only even lanes
// hold the correct result and write. Must be called by full waves.
__device__ __forceinline__ unsigned int packpair(float v) {
    float vn = __shfl_xor(v, 1, 64);
    U32H2 r; r.h.x = (_Float16)v; r.h.y = (_Float16)vn;
    return r.u;
}

// Raw barrier: LDS ordering only — global (weight) loads stay in flight
// across it (m201/T4 pattern). __syncthreads would drain vmcnt(0) and kill
// the cross-stage weight prefetch pipeline.
__device__ __forceinline__ void barx() {
    asm volatile("s_waitcnt lgkmcnt(0)");
    __builtin_amdgcn_s_barrier();
    __builtin_amdgcn_sched_barrier(0);
}

// ---- weight prep: fp32 -> k-pair-interleaved half2 ----
extern "C" __global__ void __launch_bounds__(256)
convert_w(const float* __restrict__ ug_w1, const float* __restrict__ ug_w2,
          const float* __restrict__ ugt_w1, const float* __restrict__ ugt_w2,
          const float* __restrict__ rg_w1, const float* __restrict__ rg_w2,
          const float* __restrict__ ns_w1, const float* __restrict__ ns_w2,
          const float* __restrict__ dk_w1, const float* __restrict__ dec_w,
          unsigned int* __restrict__ ws)
{
    const int i = blockIdx.x * 256 + threadIdx.x;
    const float* s; int o; int cbits;
    if      (i < WU_UG2)  { s = ug_w1;  o = i;           cbits = 8; }
    else if (i < WU_UGT1) { s = ug_w2;  o = i - WU_UG2;  cbits = 8; }
    else if (i < WU_UGT2) { s = ugt_w1; o = i - WU_UGT1; cbits = 8; }
    else if (i < WU_RG1)  { s = ugt_w2; o = i - WU_UGT2; cbits = 8; }
    else if (i < WU_RG2)  { s = rg_w1;  o = i - WU_RG1;  cbits = 8; }
    else if (i < WU_NS1)  { s = rg_w2;  o = i - WU_RG2;  cbits = 8; }
    else if (i < WU_NS2)  { s = ns_w1;  o = i - WU_NS1;  cbits = 8; }
    else if (i < WU_DK1)  { s = ns_w2;  o = i - WU_NS2;  cbits = 8; }
    else if (i < WU_DEC)  { s = dk_w1;  o = i - WU_DK1;  cbits = 8; }
    else                  { s = dec_w;  o = i - WU_DEC;  cbits = 7; }
    const int C  = 1 << cbits;
    const int kp = o >> cbits;
    const int c  = o & (C - 1);
    const float v0 = s[(2 * kp) * C + c];
    const float v1 = s[(2 * kp + 1) * C + c];
    const unsigned int h0 = __half_as_ushort(__float2half(v0));
    const unsigned int h1 = __half_as_ushort(__float2half(v1));
    ws[i] = h0 | (h1 << 16);
}

// NOTE macro hygiene: no parameter may be named x/y/z/w — the body does
// .x/.y/.z/.w member access and token substitution would clobber it.
#define DOT1(acc, wv, xv) { \
    acc.x = dot2f((wv).x, (xv), acc.x); acc.y = dot2f((wv).y, (xv), acc.y); \
    acc.z = dot2f((wv).z, (xv), acc.z); acc.w = dot2f((wv).w, (xv), acc.w); }

#define G1_LOAD(A, B, C_, base) { \
    _Pragma("unroll") \
    for (int j = 0; j < 4; ++j) { const int kp = kp24 + (base) + j; \
        A[j]  = *(const uint4*)(UG1  + (size_t)kp * 256 + cl4); \
        B[j]  = *(const uint4*)(UGT1 + (size_t)kp * 256 + cl4); \
        C_[j] = *(const uint4*)(RG1  + (size_t)kp * 256 + cl4); } }

#define G1_DOT(A, B, C_, base) { \
    _Pragma("unroll") \
    for (int j = 0; j < 4; ++j) { const unsigned int xv_ = x1[(base) + j]; \
        DOT1(aA, A[j], xv_); DOT1(aB, B[j], xv_); DOT1(aC, C_[j], xv_); } }

#define G2_LOAD(A, B, C_, base) { \
    _Pragma("unroll") \
    for (int j = 0; j < 4; ++j) { const int kp = kp16 + (base) + j; \
        A[j]  = *(const uint4*)(UG2  + (size_t)kp * 256 + cl4); \
        B[j]  = *(const uint4*)(UGT2 + (size_t)kp * 256 + cl4); \
        C_[j] = *(const uint4*)(RG2  + (size_t)kp * 256 + cl4); } }

#define G2_DOT(A, B, C_, base) { \
    _Pragma("unroll") \
    for (int j = 0; j < 4; ++j) { \
        const unsigned int va_ = xa[(base) + j]; \
        const unsigned int vb_ = xb[(base) + j]; \
        const unsigned int vc_ = xc[(base) + j]; \
        DOT1(aA, A[j], va_); DOT1(aB, B[j], vb_); DOT1(aC, C_[j], vc_); } }

extern "C" __global__ void __launch_bounds__(512, 2)
rnn_decay_kernel3(const float* __restrict__ data, const float* __restrict__ ts,
                  const float* __restrict__ ug_b1, const float* __restrict__ ug_b2,
                  const float* __restrict__ ugt_b1, const float* __restrict__ ugt_b2,
                  const float* __restrict__ rg_b1, const float* __restrict__ rg_b2,
                  const float* __restrict__ ns_b1, const float* __restrict__ ns_b2,
                  const float* __restrict__ dk_b1, const float* __restrict__ dk_w2,
                  const float* __restrict__ dk_b2, const float* __restrict__ dec_b,
                  const unsigned int* __restrict__ wsu, float* __restrict__ out)
{
    __shared__ __align__(16) float s_part[8192];        // GEMV partials (reused)
    __shared__ __align__(16) unsigned int s_in_h[192];  // [ydec(128)|xh(64)] half2
    __shared__ __align__(16) unsigned int s_ns_h[192];  // [y*r (128)|xh(64)] half2
    __shared__ __align__(16) unsigned int s_y_h[128];   // y half2 (dk1 src)
    __shared__ __align__(16) unsigned int s_a_h[128];   // gate-h / ns-h half2
    __shared__ __align__(16) unsigned int s_b_h[128];
    __shared__ __align__(16) unsigned int s_c_h[128];
    __shared__ __align__(16) unsigned int s_v_h[128];   // vol half2
    __shared__ float s_ut[256];
    __shared__ float s_red[8];                          // [0..3] mask, [4..7] dk

    const int tid  = threadIdx.x;
    const int w    = tid >> 6;
    const int lane = tid & 63;
    const int c    = tid & 255;
    const int cl4  = lane << 2;                          // 4 uint cols per lane
    const int traj = blockIdx.x;

    const unsigned int* UG1  = wsu + WU_UG1;  const unsigned int* UG2  = wsu + WU_UG2;
    const unsigned int* UGT1 = wsu + WU_UGT1; const unsigned int* UGT2 = wsu + WU_UGT2;
    const unsigned int* RG1  = wsu + WU_RG1;  const unsigned int* RG2  = wsu + WU_RG2;
    const unsigned int* NS1  = wsu + WU_NS1;  const unsigned int* NS2  = wsu + WU_NS2;
    const unsigned int* DK1  = wsu + WU_DK1;  const unsigned int* DECW = wsu + WU_DEC;

    const float* dbase = data + (size_t)traj * NTP * (2 * INPUT);
    const float* tbase = ts + (size_t)traj * NTP;
    float* vol_out = out + OUT_VOL + (size_t)traj * NSTEPS * DEC_OUT;
    float* dts_out = out + OUT_DTS + (size_t)traj * NSTEPS;

    if (tid < 256)
        for (int t0 = c; t0 < NSTEPS; t0 += 256)
            dts_out[t0] = tbase[t0 + 1] - tbase[t0];

    // Hoisted per-thread constants: the weight stream thrashes L1, so these
    // per-step global reads were ~200cy L2 misses on the serial reduce paths.
    const float b1sel = ((tid >> 8) ? ugt_b1 : ug_b1)[c];
    const float b2sel = ((tid >> 8) ? ugt_b2 : ug_b2)[c];
    const float rgb1  = rg_b1[c];
    const float rgb2  = rg_b2[c];
    const float nsb1  = ns_b1[c];
    const float nsb2  = ns_b2[c];
    const float dkb1  = dk_b1[c];
    const float dkw2  = dk_w2[c];
    const float dkb2  = dk_b2[0];
    const float decb  = dec_b[tid & 127];

    float r_y = 0.f, r_yt = 0.f;
    uint4 dkP[16];            // next iteration's dk1 weights (prefetched)

    const int kp24 = w * 24;
    const int kp16 = w << 4;

    for (int t = -1; t < NSTEPS; ++t) {
        const bool first = (t < 0);

        // ---- stage x, mask partials, xh pack; fetch dt early ----
        float dt_t = 0.f;
        if (tid < 256) {
            const float xval = first ? dbase[c] : dbase[(size_t)(t + 1) * 256 + c];
            if (!first) dt_t = tbase[t + 1] - tbase[t];
            float mv = (c >= 128) ? xval : 0.f;
            mv = wred(mv);
            if (lane == 0) s_red[w] = mv;               // w in 0..3 here
            if (c < 128) {
                const unsigned int px = packpair(xval);
                if (!(lane & 1)) { s_in_h[128 + (c >> 1)] = px; s_ns_h[128 + (c >> 1)] = px; }
            }
            if (first && !(lane & 1)) s_in_h[c >> 1] = 0u;   // ydec = 0
        }

        float r_ydec = 0.f, r_u = 0.f, r_r = 0.f;
        bool maskv;

        uint4 g1a[4], g1b[4], g1c[4];       // group1 chunk0 (flies over dk-reduce)
        uint4 g2a[4], g2b[4], g2c[4];       // group2 chunk0 (flies over g1-reduce)
        uint4 nsP[24];                      // ns1 weights  (fly over g2-reduce)
        uint4 nsQ[16];                      // ns2 weights  (fly over ns1-reduce)

        if (!first) {
            // ---- dk1: y @ dk_w1, K=256 — weights already in dkP ----
            unsigned int yv[16];
            {
                const uint4* sy = (const uint4*)(s_y_h + kp16);
                #pragma unroll
                for (int j = 0; j < 4; ++j) {
                    const uint4 q = sy[j];
                    yv[4*j+0] = q.x; yv[4*j+1] = q.y; yv[4*j+2] = q.z; yv[4*j+3] = q.w;
                }
            }
            float4 aD = make_float4(0.f, 0.f, 0.f, 0.f);
            #pragma unroll
            for (int j = 0; j < 16; ++j) DOT1(aD, dkP[j], yv[j]);

            G1_LOAD(g1a, g1b, g1c, 0);      // prefetch: covers B1..B3 region

            *(float4*)(s_part + (w << 8) + cl4) = aD;
            barx();                                            // B1
            if (tid < 256) {
                float v = dkb1;
                #pragma unroll
                for (int i = 0; i < 8; ++i) v += s_part[(i << 8) + c];
                v = fmaxf(v, 0.f);
                const float pv = wred(v * dkw2);
                if (lane == 0) s_red[4 + w] = pv;
            }
            barx();                                            // B2
            const float decay = fmaxf(s_red[4] + s_red[5] + s_red[6] + s_red[7] + dkb2, 0.f);
            maskv = (s_red[0] + s_red[1] + s_red[2] + s_red[3]) > 0.f;
            if (tid < 256) {
                const float diff = r_y - r_yt;
                const float ef = __expf(-decay * dt_t);
                const float eh = __expf(-0.5f * decay * dt_t);
                r_ydec = r_yt + diff * ef;
                const float vol = 0.5f * (r_y + r_yt + diff * eh);
                const unsigned int pd  = packpair(r_ydec);
                const unsigned int pvv = packpair(vol);
                if (!(lane & 1)) { s_in_h[c >> 1] = pd; s_v_h[c >> 1] = pvv; }
            }
            barx();                                            // B3
        } else {
            G1_LOAD(g1a, g1b, g1c, 0);
            barx();                                            // B3
            maskv = (s_red[0] + s_red[1] + s_red[2] + s_red[3]) > 0.f;
        }

        // ---- dec (K=256, src s_v_h) ----
        if (!first) {
            float4 aE = make_float4(0.f, 0.f, 0.f, 0.f);
            const int hh = lane >> 5, cl = (lane & 31) << 2;
            const int kpb = kp16 + hh;
            #pragma unroll 4
            for (int i = 0; i < 8; ++i) {
                const int kp = kpb + (i << 1);
                const uint4 wv = *(const uint4*)(DECW + (size_t)kp * 128 + cl);
                const unsigned int xv_ = s_v_h[kp];
                DOT1(aE, wv, xv_);
            }
            *(float4*)(s_part + 6144 + ((w << 1) + hh) * 128 + cl) = aE;
        }

        // ---- group1: ug1/ugt1/rg1 (K=384, src s_in_h), reg-double-buffered ----
        {
            unsigned int x1[24];
            {
                const uint4* sx = (const uint4*)(s_in_h + kp24);
                #pragma unroll
                for (int j = 0; j < 6; ++j) {
                    const uint4 q = sx[j];
                    x1[4*j+0] = q.x; x1[4*j+1] = q.y; x1[4*j+2] = q.z; x1[4*j+3] = q.w;
                }
            }
            float4 aA = make_float4(0.f,0.f,0.f,0.f), aB = aA, aC = aA;
            uint4 qa[4], qb[4], qc[4];
            G1_LOAD(qa, qb, qc, 4);     G1_DOT(g1a, g1b, g1c, 0);
            G1_LOAD(g1a, g1b, g1c, 8);  G1_DOT(qa, qb, qc, 4);
            G1_LOAD(qa, qb, qc, 12);    G1_DOT(g1a, g1b, g1c, 8);
            G1_LOAD(g1a, g1b, g1c, 16); G1_DOT(qa, qb, qc, 12);
            G1_LOAD(qa, qb, qc, 20);    G1_DOT(g1a, g1b, g1c, 16);
            G1_DOT(qa, qb, qc, 20);
            G2_LOAD(g2a, g2b, g2c, 0);  // prefetch: covers B4..B5 region
            *(float4*)(s_part + (w << 8) + cl4)          = aA;
            *(float4*)(s_part + 2048 + (w << 8) + cl4)   = aB;
            *(float4*)(s_part + 4096 + (w << 8) + cl4)   = aC;
        }
        barx();                                                // B4
        {   // reduce + tanh + pack to half2 srcs
            const int s = tid >> 8;
            float v = b1sel;
            const float* pb = s_part + (s ? 2048 : 0) + c;
            #pragma unroll
            for (int i = 0; i < 8; ++i) v += pb[i << 8];
            v = fast_tanh(v);
            const unsigned int pk = packpair(v);
            if (!(lane & 1)) (s ? s_b_h : s_a_h)[c >> 1] = pk;
            if (tid < 256) {
                float v2 = rgb1;
                const float* pb2 = s_part + 4096 + c;
                #pragma unroll
                for (int i = 0; i < 8; ++i) v2 += pb2[i << 8];
                v2 = fast_tanh(v2);
                const unsigned int pk2 = packpair(v2);
                if (!(lane & 1)) s_c_h[c >> 1] = pk2;
            }
            if (!first && tid < 128) {
                float vd = decb;
                const float* pbd = s_part + 6144 + tid;
                #pragma unroll
                for (int i = 0; i < 16; ++i) vd += pbd[i << 7];
                vol_out[(size_t)t * DEC_OUT + tid] = vd;
            }
        }
        barx();                                                // B5

        // ---- group2: ug2/ugt2/rg2 (K=256; srcs s_a_h, s_b_h, s_c_h) ----
        {
            unsigned int xa[16], xb[16], xc[16];
            {
                const uint4* pa_ = (const uint4*)(s_a_h + kp16);
                const uint4* pb_ = (const uint4*)(s_b_h + kp16);
                const uint4* pc_ = (const uint4*)(s_c_h + kp16);
                #pragma unroll
                for (int j = 0; j < 4; ++j) {
                    uint4 q = pa_[j]; xa[4*j+0]=q.x; xa[4*j+1]=q.y; xa[4*j+2]=q.z; xa[4*j+3]=q.w;
                    q = pb_[j];       xb[4*j+0]=q.x; xb[4*j+1]=q.y; xb[4*j+2]=q.z; xb[4*j+3]=q.w;
                    q = pc_[j];       xc[4*j+0]=q.x; xc[4*j+1]=q.y; xc[4*j+2]=q.z; xc[4*j+3]=q.w;
                }
            }
            float4 aA = make_float4(0.f,0.f,0.f,0.f), aB = aA, aC = aA;
            uint4 qa[4], qb[4], qc[4];
            G2_LOAD(qa, qb, qc, 4);     G2_DOT(g2a, g2b, g2c, 0);
            G2_LOAD(g2a, g2b, g2c, 8);  G2_DOT(qa, qb, qc, 4);
            G2_LOAD(qa, qb, qc, 12);    G2_DOT(g2a, g2b, g2c, 8);
            G2_DOT(qa, qb, qc, 12);
            #pragma unroll
            for (int j = 0; j < 24; ++j)   // prefetch ns1: covers B6..B7 region
                nsP[j] = *(const uint4*)(NS1 + (size_t)(kp24 + j) * 256 + cl4);
            *(float4*)(s_part + (w << 8) + cl4)          = aA;
            *(float4*)(s_part + 2048 + (w << 8) + cl4)   = aB;
            *(float4*)(s_part + 4096 + (w << 8) + cl4)   = aC;
        }
        barx();                                                // B6
        {
            const int s = tid >> 8;
            float v = b2sel;
            const float* pb = s_part + (s ? 2048 : 0) + c;
            #pragma unroll
            for (int i = 0; i < 8; ++i) v += pb[i << 8];
            v = fast_sigmoid(v);
            if (s) s_ut[c] = v; else r_u = v;
            if (tid < 256) {
                float v2 = rgb2;
                const float* pb2 = s_part + 4096 + c;
                #pragma unroll
                for (int i = 0; i < 8; ++i) v2 += pb2[i << 8];
                r_r = fast_sigmoid(v2);
                const unsigned int pk = packpair(r_ydec * r_r);
                if (!(lane & 1)) s_ns_h[c >> 1] = pk;
            }
        }
        barx();                                                // B7

        // ---- ns1 (K=384, src s_ns_h) — weights already in nsP ----
        {
            unsigned int xn[24];
            {
                const uint4* sn = (const uint4*)(s_ns_h + kp24);
                #pragma unroll
                for (int j = 0; j < 6; ++j) {
                    const uint4 q = sn[j];
                    xn[4*j+0] = q.x; xn[4*j+1] = q.y; xn[4*j+2] = q.z; xn[4*j+3] = q.w;
                }
            }
            float4 aA = make_float4(0.f,0.f,0.f,0.f);
            #pragma unroll
            for (int j = 0; j < 24; ++j) DOT1(aA, nsP[j], xn[j]);
            #pragma unroll
            for (int j = 0; j < 16; ++j)   // prefetch ns2: covers B8..B9 region
                nsQ[j] = *(const uint4*)(NS2 + (size_t)(kp16 + j) * 256 + cl4);
            *(float4*)(s_part + (w << 8) + cl4) = aA;
        }
        barx();                                                // B8
        if (tid < 256) {
            float v = nsb1;
            #pragma unroll
            for (int i = 0; i < 8; ++i) v += s_part[(i << 8) + c];
            v = fast_tanh(v);
            const unsigned int pk = packpair(v);
            if (!(lane & 1)) s_a_h[c >> 1] = pk;
        }
        barx();                                                // B9

        // ---- ns2 (K=256, src s_a_h) — weights already in nsQ ----
        {
            unsigned int xs[16];
            {
                const uint4* sa = (const uint4*)(s_a_h + kp16);
                #pragma unroll
                for (int j = 0; j < 4; ++j) {
                    const uint4 q = sa[j];
                    xs[4*j+0] = q.x; xs[4*j+1] = q.y; xs[4*j+2] = q.z; xs[4*j+3] = q.w;
                }
            }
            float4 aA = make_float4(0.f,0.f,0.f,0.f);
            #pragma unroll
            for (int j = 0; j < 16; ++j) DOT1(aA, nsQ[j], xs[j]);
            #pragma unroll
            for (int j = 0; j < 16; ++j)   // prefetch next-step dk1: covers B10..B11 + x-stage
                dkP[j] = *(const uint4*)(DK1 + (size_t)(kp16 + j) * 256 + cl4);
            *(float4*)(s_part + (w << 8) + cl4) = aA;
        }
        barx();                                                // B10
        if (tid < 256) {
            float nsv = nsb2;
            #pragma unroll
            for (int i = 0; i < 8; ++i) nsv += s_part[(i << 8) + c];
            const float u = r_u, ut = s_ut[c];
            const float ny  = (1.f - u)  * nsv + u  * r_ydec;
            const float nyt = (1.f - ut) * nsv + ut * r_yt;
            r_y  = maskv ? ny  : r_ydec;
            r_yt = maskv ? nyt : r_yt;
            const unsigned int pk = packpair(r_y);
            if (!(lane & 1)) s_y_h[c >> 1] = pk;
        }
        barx();                                                // B11
    }

    if (tid < 256)
        out[(size_t)traj * 256 + c] = r_y;
}

extern "C" void kernel_launch(void* const* d_in, const int* in_sizes, int n_in,
                              void* d_out, int out_size, void* d_ws, size_t ws_size,
                              hipStream_t stream) {
    const float* data   = (const float*)d_in[0];
    const float* ts     = (const float*)d_in[1];
    const float* ug_w1  = (const float*)d_in[2];
    const float* ug_b1  = (const float*)d_in[3];
    const float* ug_w2  = (const float*)d_in[4];
    const float* ug_b2  = (const float*)d_in[5];
    const float* ugt_w1 = (const float*)d_in[6];
    const float* ugt_b1 = (const float*)d_in[7];
    const float* ugt_w2 = (const float*)d_in[8];
    const float* ugt_b2 = (const float*)d_in[9];
    const float* rg_w1  = (const float*)d_in[10];
    const float* rg_b1  = (const float*)d_in[11];
    const float* rg_w2  = (const float*)d_in[12];
    const float* rg_b2  = (const float*)d_in[13];
    // d_in[14..17] = rgt_* : unused by the reference
    const float* ns_w1  = (const float*)d_in[18];
    const float* ns_b1  = (const float*)d_in[19];
    const float* ns_w2  = (const float*)d_in[20];
    const float* ns_b2  = (const float*)d_in[21];
    const float* dk_w1  = (const float*)d_in[22];
    const float* dk_b1  = (const float*)d_in[23];
    const float* dk_w2  = (const float*)d_in[24];
    const float* dk_b2  = (const float*)d_in[25];
    const float* dec_w  = (const float*)d_in[26];
    const float* dec_b  = (const float*)d_in[27];

    unsigned int* wsu = (unsigned int*)d_ws;

    convert_w<<<WU_TOT / 256, 256, 0, stream>>>(ug_w1, ug_w2, ugt_w1, ugt_w2,
                                                rg_w1, rg_w2, ns_w1, ns_w2,
                                                dk_w1, dec_w, wsu);

    rnn_decay_kernel3<<<NTRAJ, 512, 0, stream>>>(
        data, ts, ug_b1, ug_b2, ugt_b1, ugt_b2, rg_b1, rg_b2, ns_b1, ns_b2,
        dk_b1, dk_w2, dk_b2, dec_b, wsu, (float*)d_out);
}